// Round 1
// baseline (5531.412 us; speedup 1.0000x reference)
//
#include <hip/hip_runtime.h>

// Encoder: 2-layer LSTM (H1=64, H2=32, IN=2), B=512, T=4096, + FC [32->16].
// One block per batch element (512 blocks x 256 threads, 2 blocks/CU).
// Weights in VGPRs (loaded once, reused 4096 steps); h-state in double-buffered
// LDS; one __syncthreads per step; gate exchange via intra-quad shuffles.

#define TT 4096
#define BB 512

__device__ __forceinline__ float fexp2(float x) { return __builtin_amdgcn_exp2f(x); }
__device__ __forceinline__ float frcp(float x)  { return __builtin_amdgcn_rcpf(x); }
// sigmoid(x) = 1/(1+e^-x) = rcp(1 + 2^(-x*log2e))
__device__ __forceinline__ float sigm(float x)  { return frcp(1.0f + fexp2(x * -1.4426950408889634f)); }
// tanh(x) = 1 - 2/(1 + e^{2x}) ; overflow-safe at both ends
__device__ __forceinline__ float tanh_(float x) { return 1.0f - 2.0f * frcp(1.0f + fexp2(x * 2.8853900817779268f)); }

__global__ __launch_bounds__(256, 2) void lstm_enc_kernel(
    const float* __restrict__ x,
    const float* __restrict__ Wih1, const float* __restrict__ Whh1,
    const float* __restrict__ bih1, const float* __restrict__ bhh1,
    const float* __restrict__ Wih2, const float* __restrict__ Whh2,
    const float* __restrict__ bih2, const float* __restrict__ bhh2,
    const float* __restrict__ Wfc,  const float* __restrict__ bfc,
    float* __restrict__ out)
{
    const int tid  = threadIdx.x;
    const int lane = tid & 63;
    const int b    = blockIdx.x;

    // L1 mapping: thread = 4*unit + gate_class  (class 0..3 = i,f,g,o)
    const int j1   = tid >> 2;          // unit 0..63
    const int g1c  = tid & 3;           // gate class
    const int row1 = g1c * 64 + j1;     // row in [4H1, *] weight matrices

    // L2 mapping: gate slot m = tid>>1 (each gate split across a lane pair)
    const int m2   = tid >> 1;          // 0..127
    const int half = tid & 1;           // which half of the 96-dot
    const int j2   = m2 >> 2;           // unit 0..31
    const int g2c  = m2 & 3;            // gate class
    const int row2 = g2c * 32 + j2;

    __shared__ float h1s[2][64];
    __shared__ float h2s[2][32];
    __shared__ float xs[2][128];        // 64 steps of x (2 floats/step), double-buffered

    // ---- load weights into registers (live for all 4096 steps) ----
    float w1[64];
    {
        const float4* src = (const float4*)(Whh1 + row1 * 64);
        float4* dst = (float4*)w1;
        #pragma unroll
        for (int k = 0; k < 16; ++k) dst[k] = src[k];
    }
    const float wx0 = Wih1[row1 * 2 + 0];
    const float wx1 = Wih1[row1 * 2 + 1];
    const float bb1 = bih1[row1] + bhh1[row1];

    // L2: 96-element row (Wih2 64 + Whh2 32) split 48/48 across the lane pair:
    //   half0: Wih2[row2][0:48]
    //   half1: Wih2[row2][48:64] ++ Whh2[row2][0:32]
    float w2[48];
    if (half == 0) {
        const float4* src = (const float4*)(Wih2 + row2 * 64);
        float4* dst = (float4*)w2;
        #pragma unroll
        for (int k = 0; k < 12; ++k) dst[k] = src[k];
    } else {
        const float4* s0 = (const float4*)(Wih2 + row2 * 64 + 48);
        const float4* s1 = (const float4*)(Whh2 + row2 * 32);
        float4* dst = (float4*)w2;
        #pragma unroll
        for (int k = 0; k < 4; ++k) dst[k] = s0[k];
        #pragma unroll
        for (int k = 0; k < 8; ++k) dst[4 + k] = s1[k];
    }
    const float bb2 = bih2[row2] + bhh2[row2];

    const float* xb = x + (size_t)b * (TT * 2);

    // ---- init state + first x chunk ----
    if (tid < 64)  h1s[0][tid] = 0.0f;
    if (tid < 32)  h2s[0][tid] = 0.0f;
    if (tid < 128) xs[0][tid]  = xb[tid];
    __syncthreads();

    float cc1 = 0.0f, cc2 = 0.0f;

    for (int t = 0; t < TT; ++t) {
        const int p  = t & 1;       // read buffer
        const int q  = p ^ 1;       // write buffer
        const int cb = (t >> 6) & 1;

        // stage next 64-step x chunk (issue load early, store late)
        float xstage = 0.0f;
        const bool do_stage = ((t & 63) == 0) && (t + 64 < TT) && (tid < 128);
        if (do_stage) xstage = xb[(t + 64) * 2 + tid];

        const float x0 = xs[cb][((t & 63) << 1) + 0];
        const float x1 = xs[cb][((t & 63) << 1) + 1];

        // ---------------- layer 1: pre-activation for this thread's gate ----------------
        float pre;
        {
            const float4* h4 = (const float4*)h1s[p];
            float s0 = 0.f, s1 = 0.f, s2 = 0.f, s3 = 0.f;
            #pragma unroll
            for (int k = 0; k < 16; ++k) {
                const float4 hv = h4[k];               // wave-uniform broadcast read
                s0 = fmaf(w1[4*k+0], hv.x, s0);
                s1 = fmaf(w1[4*k+1], hv.y, s1);
                s2 = fmaf(w1[4*k+2], hv.z, s2);
                s3 = fmaf(w1[4*k+3], hv.w, s3);
            }
            pre = fmaf(wx0, x0, fmaf(wx1, x1, bb1)) + ((s0 + s1) + (s2 + s3));
        }
        const float a1 = (g1c == 2) ? tanh_(pre) : sigm(pre);
        // gather i,f,g,o of this thread's unit from the quad
        const int qb = lane & ~3;
        const float gi = __shfl(a1, qb + 0, 64);
        const float gf = __shfl(a1, qb + 1, 64);
        const float gg = __shfl(a1, qb + 2, 64);
        const float go = __shfl(a1, qb + 3, 64);
        cc1 = fmaf(gf, cc1, gi * gg);                  // all 4 quad lanes keep a copy
        const float h1v = go * tanh_(cc1);
        if (g1c == 0) h1s[q][j1] = h1v;

        if (do_stage) xs[cb ^ 1][tid] = xstage;

        __syncthreads();   // h1(t) visible; h2(t-1) reads below are ordered too

        // ---------------- layer 2: half-row dot per lane, pair-combined ----------------
        float pre2;
        {
            const float4* n4 = (const float4*)h1s[q];  // new h1 (this step)
            const float4* e4 = (const float4*)h2s[p];  // h2 from previous step
            float s0 = 0.f, s1 = 0.f, s2 = 0.f, s3 = 0.f;
            if (half == 0) {
                #pragma unroll
                for (int k = 0; k < 12; ++k) {
                    const float4 hv = n4[k];
                    s0 = fmaf(w2[4*k+0], hv.x, s0);
                    s1 = fmaf(w2[4*k+1], hv.y, s1);
                    s2 = fmaf(w2[4*k+2], hv.z, s2);
                    s3 = fmaf(w2[4*k+3], hv.w, s3);
                }
                pre2 = (s0 + s1) + (s2 + s3);
            } else {
                #pragma unroll
                for (int k = 0; k < 4; ++k) {
                    const float4 hv = n4[12 + k];
                    s0 = fmaf(w2[4*k+0], hv.x, s0);
                    s1 = fmaf(w2[4*k+1], hv.y, s1);
                    s2 = fmaf(w2[4*k+2], hv.z, s2);
                    s3 = fmaf(w2[4*k+3], hv.w, s3);
                }
                #pragma unroll
                for (int k = 0; k < 8; ++k) {
                    const float4 hv = e4[k];
                    s0 = fmaf(w2[16 + 4*k+0], hv.x, s0);
                    s1 = fmaf(w2[16 + 4*k+1], hv.y, s1);
                    s2 = fmaf(w2[16 + 4*k+2], hv.z, s2);
                    s3 = fmaf(w2[16 + 4*k+3], hv.w, s3);
                }
                pre2 = bb2 + ((s0 + s1) + (s2 + s3));
            }
        }
        pre2 += __shfl_xor(pre2, 1, 64);               // combine the two halves
        const float a2 = (g2c == 2) ? tanh_(pre2) : sigm(pre2);
        // unit j2's gates live in this 8-lane group at offsets 0,2,4,6
        const int ob = lane & ~7;
        const float i2 = __shfl(a2, ob + 0, 64);
        const float f2 = __shfl(a2, ob + 2, 64);
        const float g2 = __shfl(a2, ob + 4, 64);
        const float o2 = __shfl(a2, ob + 6, 64);
        cc2 = fmaf(f2, cc2, i2 * g2);
        const float h2v = o2 * tanh_(cc2);
        if ((tid & 7) == 0) h2s[q][j2] = h2v;
        // no trailing barrier needed: next step's conflicting accesses are all
        // separated from this step's by the mid-step barrier (double buffers)
    }

    __syncthreads();
    // final h2 is in h2s[0]  (t=4095: q = ((4095&1)^1) = 0)
    if (tid < 16) {
        float s = bfc[tid];
        const float* wr = Wfc + tid * 32;
        #pragma unroll
        for (int k = 0; k < 32; ++k) s = fmaf(wr[k], h2s[0][k], s);
        out[b * 16 + tid] = s;
    }
}

extern "C" void kernel_launch(void* const* d_in, const int* in_sizes, int n_in,
                              void* d_out, int out_size, void* d_ws, size_t ws_size,
                              hipStream_t stream) {
    const float* x    = (const float*)d_in[0];
    const float* Wih1 = (const float*)d_in[1];
    const float* Whh1 = (const float*)d_in[2];
    const float* bih1 = (const float*)d_in[3];
    const float* bhh1 = (const float*)d_in[4];
    const float* Wih2 = (const float*)d_in[5];
    const float* Whh2 = (const float*)d_in[6];
    const float* bih2 = (const float*)d_in[7];
    const float* bhh2 = (const float*)d_in[8];
    const float* Wfc  = (const float*)d_in[9];
    const float* bfc  = (const float*)d_in[10];

    lstm_enc_kernel<<<dim3(BB), dim3(256), 0, stream>>>(
        x, Wih1, Whh1, bih1, bhh1, Wih2, Whh2, bih2, bhh2, Wfc, bfc,
        (float*)d_out);
}

// Round 2
// 5090.778 us; speedup vs baseline: 1.0866x; 1.0866x over previous
//
#include <hip/hip_runtime.h>

// Encoder: 2-layer LSTM (H1=64, H2=32, IN=2), B=512, T=4096, + FC [32->16].
// R2 design: LDS-pipe was the bottleneck (broadcast ds_read_b128 x 8 waves).
// Now h-vectors live lane-distributed in registers; dot-product broadcasts go
// through v_readlane (VALU) instead of LDS; gate exchange via DPP quad_perm.
// L2 runs software-pipelined one step behind L1 so both phases share one
// barrier and one h1 broadcast per iteration. Wave specialization:
//   waves 2,3: layer-1 (2 gate-rows per lane, units = lane/2)
//   waves 0,1: layer-2 (1 full 96-wide gate-row per lane, quad = 4 gates)

#define TT 4096
#define BB 512

__device__ __forceinline__ float fexp2(float x){ return __builtin_amdgcn_exp2f(x); }
__device__ __forceinline__ float frcp (float x){ return __builtin_amdgcn_rcpf(x); }
__device__ __forceinline__ float sigm (float x){ return frcp(1.0f + fexp2(x * -1.4426950408889634f)); }
__device__ __forceinline__ float tanh_(float x){ return 1.0f - 2.0f * frcp(1.0f + fexp2(x * 2.8853900817779268f)); }

__device__ __forceinline__ float rlane(float v, int l){
  return __builtin_bit_cast(float, __builtin_amdgcn_readlane(__builtin_bit_cast(int, v), l));
}
// DPP quad-perm cross-lane move (VALU, no LDS pipe)
template<int CTRL>
__device__ __forceinline__ float qperm(float v){
  return __builtin_bit_cast(float,
      __builtin_amdgcn_update_dpp(0, __builtin_bit_cast(int, v), CTRL, 0xF, 0xF, true));
}

__global__ __launch_bounds__(256, 2) void lstm_enc_kernel(
    const float* __restrict__ x,
    const float* __restrict__ Wih1, const float* __restrict__ Whh1,
    const float* __restrict__ bih1, const float* __restrict__ bhh1,
    const float* __restrict__ Wih2, const float* __restrict__ Whh2,
    const float* __restrict__ bih2, const float* __restrict__ bhh2,
    const float* __restrict__ Wfc,  const float* __restrict__ bfc,
    float* __restrict__ out)
{
    const int tid  = threadIdx.x;
    const int l    = tid & 63;          // lane
    const int wv   = tid >> 6;          // wave 0..3
    const int b    = blockIdx.x;
    const bool isL1 = (wv >= 2);        // waves 2,3 -> layer 1; waves 0,1 -> layer 2

    __shared__ float h1s[2][64];
    __shared__ float h2s[2][32];

    // ---- weights in registers; one array, per-role layout ----
    // L1 (waves 2,3): lane pair = unit j; gp=l&1 selects gates (i,f) or (g,o).
    //   wreg[0:64]  = Whh1[row rA], wreg[64:128] = Whh1[row rB]
    // L2 (waves 0,1): lane quad = unit u, g=l&3 gate class.
    //   wreg[0:64]  = Wih2[row2],  wreg[64:96]  = Whh2[row2]
    float wreg[128];
    // L1 extras
    int   j1 = 0, gp = 0;
    float wxA0=0.f, wxA1=0.f, wxB0=0.f, wxB1=0.f, bbA=0.f, bbB=0.f;
    // L2 extras
    int   u2 = 0, g2 = 0;
    float bb2 = 0.f;

    if (isL1) {
        j1 = (wv - 2) * 32 + (l >> 1);
        gp = l & 1;
        const int rA = (2 * gp) * 64 + j1;   // gate 2*gp
        const int rB = rA + 64;              // gate 2*gp+1
        {
            const float4* sA = (const float4*)(Whh1 + rA * 64);
            const float4* sB = (const float4*)(Whh1 + rB * 64);
            float4* dA = (float4*)wreg;
            float4* dB = (float4*)(wreg + 64);
            #pragma unroll
            for (int k = 0; k < 16; ++k) { dA[k] = sA[k]; dB[k] = sB[k]; }
        }
        wxA0 = Wih1[rA*2+0]; wxA1 = Wih1[rA*2+1];
        wxB0 = Wih1[rB*2+0]; wxB1 = Wih1[rB*2+1];
        bbA = bih1[rA] + bhh1[rA];
        bbB = bih1[rB] + bhh1[rB];
    } else {
        u2 = wv * 16 + (l >> 2);
        g2 = l & 3;
        const int row2 = g2 * 32 + u2;
        {
            const float4* s0 = (const float4*)(Wih2 + row2 * 64);
            const float4* s1 = (const float4*)(Whh2 + row2 * 32);
            float4* d0 = (float4*)wreg;
            float4* d1 = (float4*)(wreg + 64);
            #pragma unroll
            for (int k = 0; k < 16; ++k) d0[k] = s0[k];
            #pragma unroll
            for (int k = 0; k < 8;  ++k) d1[k] = s1[k];
        }
        bb2 = bih2[row2] + bhh2[row2];
    }

    const float* xb = x + (size_t)b * (TT * 2);

    // x staged in registers: lane l holds the float2 for step (chunk*64 + l)
    float2 vx = make_float2(0.f, 0.f), vxn = make_float2(0.f, 0.f);
    if (isL1) vxn = ((const float2*)xb)[l];          // chunk 0

    if (tid < 64) h1s[0][tid] = 0.0f;
    if (tid < 32) { h2s[0][tid] = 0.0f; h2s[1][tid] = 0.0f; }
    __syncthreads();

    float cc1 = 0.0f, cc2 = 0.0f;

    for (int t = 0; t < TT; ++t) {
        const int rb = t & 1;
        const int wb = rb ^ 1;

        // h1(t-1), lane-distributed: lane m in [0,16) holds h1[4m..4m+3]
        const float4 vh1 = ((const float4*)h1s[rb])[l & 15];

        if (isL1) {
            // ---------------- layer 1, step t ----------------
            if ((t & 63) == 0) {
                vx = vxn;
                if (t + 64 < TT) vxn = ((const float2*)xb)[(t >> 6) * 64 + 64 + l];
            }
            const float x0 = rlane(vx.x, t & 63);
            const float x1 = rlane(vx.y, t & 63);

            float aA0=0.f,aA1=0.f,aA2=0.f,aA3=0.f;
            float aB0=0.f,aB1=0.f,aB2=0.f,aB3=0.f;
            #pragma unroll
            for (int k = 0; k < 16; ++k) {
                const float s0 = rlane(vh1.x, k);
                const float s1 = rlane(vh1.y, k);
                const float s2 = rlane(vh1.z, k);
                const float s3 = rlane(vh1.w, k);
                aA0 = fmaf(wreg[4*k+0],    s0, aA0);
                aA1 = fmaf(wreg[4*k+1],    s1, aA1);
                aA2 = fmaf(wreg[4*k+2],    s2, aA2);
                aA3 = fmaf(wreg[4*k+3],    s3, aA3);
                aB0 = fmaf(wreg[64+4*k+0], s0, aB0);
                aB1 = fmaf(wreg[64+4*k+1], s1, aB1);
                aB2 = fmaf(wreg[64+4*k+2], s2, aB2);
                aB3 = fmaf(wreg[64+4*k+3], s3, aB3);
            }
            const float preA = ((aA0+aA1)+(aA2+aA3)) + fmaf(wxA0, x0, fmaf(wxA1, x1, bbA));
            const float preB = ((aB0+aB1)+(aB2+aB3)) + fmaf(wxB0, x0, fmaf(wxB1, x1, bbB));

            // gp==0: gates (i,f) -> sigm,sigm ; gp==1: gates (g,o) -> tanh,sigm
            const float actA = gp ? tanh_(preA) : sigm(preA);
            const float actB = sigm(preB);
            // pair exchange within quad: [1,0,3,2]
            const float pA = qperm<0xB1>(actA);
            const float pB = qperm<0xB1>(actB);
            const float gi = gp ? pA   : actA;
            const float gf = gp ? pB   : actB;
            const float gg = gp ? actA : pA;
            const float go = gp ? actB : pB;
            cc1 = fmaf(gf, cc1, gi * gg);
            const float h1v = go * tanh_(cc1);
            if (gp == 0) h1s[wb][j1] = h1v;
        } else {
            // ---------------- layer 2, step t-1 (pipelined) ----------------
            if (t > 0) {
                // h2(t-2), lane-distributed: lane m in [0,8) holds h2[4m..4m+3]
                const float4 vh2 = ((const float4*)h2s[rb])[l & 7];
                float a0=0.f,a1=0.f,a2=0.f,a3=0.f;
                #pragma unroll
                for (int k = 0; k < 16; ++k) {
                    a0 = fmaf(wreg[4*k+0], rlane(vh1.x, k), a0);
                    a1 = fmaf(wreg[4*k+1], rlane(vh1.y, k), a1);
                    a2 = fmaf(wreg[4*k+2], rlane(vh1.z, k), a2);
                    a3 = fmaf(wreg[4*k+3], rlane(vh1.w, k), a3);
                }
                #pragma unroll
                for (int k = 0; k < 8; ++k) {
                    a0 = fmaf(wreg[64+4*k+0], rlane(vh2.x, k), a0);
                    a1 = fmaf(wreg[64+4*k+1], rlane(vh2.y, k), a1);
                    a2 = fmaf(wreg[64+4*k+2], rlane(vh2.z, k), a2);
                    a3 = fmaf(wreg[64+4*k+3], rlane(vh2.w, k), a3);
                }
                const float pre2 = bb2 + ((a0+a1)+(a2+a3));
                const float act2 = (g2 == 2) ? tanh_(pre2) : sigm(pre2);
                const float i2 = qperm<0x00>(act2);
                const float f2 = qperm<0x55>(act2);
                const float g2v= qperm<0xAA>(act2);
                const float o2 = qperm<0xFF>(act2);
                cc2 = fmaf(f2, cc2, i2 * g2v);
                const float h2v = o2 * tanh_(cc2);
                if (g2 == 0) h2s[wb][u2] = h2v;
            }
        }
        __syncthreads();
    }

    // ---- epilogue: layer 2, step TT-1 ----
    // h1(4095) is in h1s[0]; h2(4094) is in h2s[0].
    if (!isL1) {
        const float4 vh1 = ((const float4*)h1s[0])[l & 15];
        const float4 vh2 = ((const float4*)h2s[0])[l & 7];
        float a0=0.f,a1=0.f,a2=0.f,a3=0.f;
        #pragma unroll
        for (int k = 0; k < 16; ++k) {
            a0 = fmaf(wreg[4*k+0], rlane(vh1.x, k), a0);
            a1 = fmaf(wreg[4*k+1], rlane(vh1.y, k), a1);
            a2 = fmaf(wreg[4*k+2], rlane(vh1.z, k), a2);
            a3 = fmaf(wreg[4*k+3], rlane(vh1.w, k), a3);
        }
        #pragma unroll
        for (int k = 0; k < 8; ++k) {
            a0 = fmaf(wreg[64+4*k+0], rlane(vh2.x, k), a0);
            a1 = fmaf(wreg[64+4*k+1], rlane(vh2.y, k), a1);
            a2 = fmaf(wreg[64+4*k+2], rlane(vh2.z, k), a2);
            a3 = fmaf(wreg[64+4*k+3], rlane(vh2.w, k), a3);
        }
        const float pre2 = bb2 + ((a0+a1)+(a2+a3));
        const float act2 = (g2 == 2) ? tanh_(pre2) : sigm(pre2);
        const float i2 = qperm<0x00>(act2);
        const float f2 = qperm<0x55>(act2);
        const float g2v= qperm<0xAA>(act2);
        const float o2 = qperm<0xFF>(act2);
        cc2 = fmaf(f2, cc2, i2 * g2v);
        const float h2v = o2 * tanh_(cc2);
        if (g2 == 0) h2s[1][u2] = h2v;
    }
    __syncthreads();

    if (tid < 16) {
        float s = bfc[tid];
        const float* wr = Wfc + tid * 32;
        #pragma unroll
        for (int k = 0; k < 32; ++k) s = fmaf(wr[k], h2s[1][k], s);
        out[b * 16 + tid] = s;
    }
}

extern "C" void kernel_launch(void* const* d_in, const int* in_sizes, int n_in,
                              void* d_out, int out_size, void* d_ws, size_t ws_size,
                              hipStream_t stream) {
    const float* x    = (const float*)d_in[0];
    const float* Wih1 = (const float*)d_in[1];
    const float* Whh1 = (const float*)d_in[2];
    const float* bih1 = (const float*)d_in[3];
    const float* bhh1 = (const float*)d_in[4];
    const float* Wih2 = (const float*)d_in[5];
    const float* Whh2 = (const float*)d_in[6];
    const float* bih2 = (const float*)d_in[7];
    const float* bhh2 = (const float*)d_in[8];
    const float* Wfc  = (const float*)d_in[9];
    const float* bfc  = (const float*)d_in[10];

    lstm_enc_kernel<<<dim3(BB), dim3(256), 0, stream>>>(
        x, Wih1, Whh1, bih1, bhh1, Wih2, Whh2, bih2, bhh2, Wfc, bfc,
        (float*)d_out);
}

// Round 3
// 5027.665 us; speedup vs baseline: 1.1002x; 1.0126x over previous
//
#include <hip/hip_runtime.h>

// Encoder: 2-layer LSTM (H1=64, H2=32, IN=2), B=512, T=4096, + FC [32->16].
// R3: R2's structure (wave specialization + 1-step L2 pipelining + DPP gate
// exchange + readlane broadcasts), but weights are loaded through a SINGLE
// unconditional code path into cleanly-typed float4 register arrays. R2's
// divergent-branch weight init (VGPR_Count=84 < 128 weight floats) proved the
// compiler demoted the weight arrays and re-streamed them every step.
//   waves 2,3: layer-1 (2 gate-rows per lane)      — wA,wB = Whh1 rows
//   waves 0,1: layer-2 (1 full 96-wide gate-row)   — wA = Wih2 row, wB[0:8] = Whh2 row

#define TT 4096
#define BB 512

__device__ __forceinline__ float fexp2(float x){ return __builtin_amdgcn_exp2f(x); }
__device__ __forceinline__ float frcp (float x){ return __builtin_amdgcn_rcpf(x); }
__device__ __forceinline__ float sigm (float x){ return frcp(1.0f + fexp2(x * -1.4426950408889634f)); }
__device__ __forceinline__ float tanh_(float x){ return 1.0f - 2.0f * frcp(1.0f + fexp2(x * 2.8853900817779268f)); }

__device__ __forceinline__ float rlane(float v, int lane){
  return __builtin_bit_cast(float, __builtin_amdgcn_readlane(__builtin_bit_cast(int, v), lane));
}
// DPP quad-perm (VALU pipe, no LDS). old = src so no zero-materialization.
template<int CTRL>
__device__ __forceinline__ float qperm(float v){
  const int s = __builtin_bit_cast(int, v);
  return __builtin_bit_cast(float, __builtin_amdgcn_update_dpp(s, s, CTRL, 0xF, 0xF, true));
}

__global__ __launch_bounds__(256, 2) void lstm_enc_kernel(
    const float* __restrict__ x,
    const float* __restrict__ Wih1, const float* __restrict__ Whh1,
    const float* __restrict__ bih1, const float* __restrict__ bhh1,
    const float* __restrict__ Wih2, const float* __restrict__ Whh2,
    const float* __restrict__ bih2, const float* __restrict__ bhh2,
    const float* __restrict__ Wfc,  const float* __restrict__ bfc,
    float* __restrict__ out)
{
    const int tid  = threadIdx.x;
    const int l    = tid & 63;
    const int wv   = tid >> 6;
    const int b    = blockIdx.x;
    const bool isL1 = (wv >= 2);

    __shared__ float h1s[2][64];
    __shared__ float h2s[2][32];

    // ---- role indices (both computed; selection is by address, not control flow) ----
    const int j1  = ((wv - 2) & 1) * 32 + (l >> 1);  // L1 unit (valid when isL1)
    const int gp  = l & 1;                            // 0: gates(i,f)  1: gates(g,o)
    const int rA1 = (2 * gp) * 64 + j1;
    const int rB1 = rA1 + 64;

    const int u2   = (wv & 1) * 16 + (l >> 2);        // L2 unit (valid when !isL1)
    const int g2   = l & 3;                           // gate class
    const int row2 = g2 * 32 + u2;

    // safe (in-bounds even for the non-selected role) scalar indices
    const int rA_s = isL1 ? rA1 : 0;
    const int rB_s = isL1 ? rB1 : 0;
    const int r2_s = isL1 ? 0   : row2;

    // ---- unified, unconditional weight load into typed float4 registers ----
    const float4* pA  = (const float4*)(isL1 ? (Whh1 + rA1 * 64) : (Wih2 + row2 * 64)); // 16 x float4
    const float4* pB1 = (const float4*)(isL1 ? (Whh1 + rB1 * 64) : (Whh2 + row2 * 32)); // 8 x float4
    const float4* pB2 = (const float4*)(isL1 ? (Whh1 + rB1 * 64 + 32) : (Whh2 + row2 * 32)); // 8 x float4 (L2: dup)

    float4 wA[16], wB[16];
    #pragma unroll
    for (int k = 0; k < 16; ++k) wA[k] = pA[k];
    #pragma unroll
    for (int k = 0; k < 8;  ++k) wB[k] = pB1[k];
    #pragma unroll
    for (int k = 0; k < 8;  ++k) wB[8 + k] = pB2[k];

    const float bbA = isL1 ? (bih1[rA_s] + bhh1[rA_s]) : (bih2[r2_s] + bhh2[r2_s]);
    const float bbB = bih1[rB_s] + bhh1[rB_s];       // meaningful for L1 only
    const float wxA0 = Wih1[rA_s * 2 + 0], wxA1 = Wih1[rA_s * 2 + 1];
    const float wxB0 = Wih1[rB_s * 2 + 0], wxB1 = Wih1[rB_s * 2 + 1];

    const float* xb = x + (size_t)b * (TT * 2);

    // x staged in registers: lane l holds float2 of step (chunk*64 + l)
    float2 vx = make_float2(0.f, 0.f), vxn = make_float2(0.f, 0.f);
    if (isL1) vxn = ((const float2*)xb)[l];          // chunk 0

    if (tid < 64) h1s[0][tid] = 0.0f;
    if (tid < 32) { h2s[0][tid] = 0.0f; h2s[1][tid] = 0.0f; }
    __syncthreads();

    float cc1 = 0.0f, cc2 = 0.0f;

    for (int t = 0; t < TT; ++t) {
        const int rb = t & 1;
        const int wb = rb ^ 1;

        // h1(t-1), lane-distributed: lane m in [0,16) holds h1[4m..4m+3]
        const float4 vh1 = ((const float4*)h1s[rb])[l & 15];

        if (isL1) {
            // ---------------- layer 1, step t ----------------
            if ((t & 63) == 0) {
                vx = vxn;
                if (t + 64 < TT) vxn = ((const float2*)xb)[(t >> 6) * 64 + 64 + l];
            }
            const float x0 = rlane(vx.x, t & 63);
            const float x1 = rlane(vx.y, t & 63);

            float aA0=0.f,aA1=0.f,aA2=0.f,aA3=0.f;
            float aB0=0.f,aB1=0.f,aB2=0.f,aB3=0.f;
            #pragma unroll
            for (int k = 0; k < 16; ++k) {
                const float s0 = rlane(vh1.x, k);
                const float s1 = rlane(vh1.y, k);
                const float s2 = rlane(vh1.z, k);
                const float s3 = rlane(vh1.w, k);
                aA0 = fmaf(wA[k].x, s0, aA0);
                aA1 = fmaf(wA[k].y, s1, aA1);
                aA2 = fmaf(wA[k].z, s2, aA2);
                aA3 = fmaf(wA[k].w, s3, aA3);
                aB0 = fmaf(wB[k].x, s0, aB0);
                aB1 = fmaf(wB[k].y, s1, aB1);
                aB2 = fmaf(wB[k].z, s2, aB2);
                aB3 = fmaf(wB[k].w, s3, aB3);
            }
            const float preA = ((aA0+aA1)+(aA2+aA3)) + fmaf(wxA0, x0, fmaf(wxA1, x1, bbA));
            const float preB = ((aB0+aB1)+(aB2+aB3)) + fmaf(wxB0, x0, fmaf(wxB1, x1, bbB));

            // gp==0: (i,f) -> sigm,sigm ; gp==1: (g,o) -> tanh,sigm
            const float actA = gp ? tanh_(preA) : sigm(preA);
            const float actB = sigm(preB);
            const float pA_ = qperm<0xB1>(actA);     // pair swap [1,0,3,2]
            const float pB_ = qperm<0xB1>(actB);
            const float gi = gp ? pA_  : actA;
            const float gf = gp ? pB_  : actB;
            const float gg = gp ? actA : pA_;
            const float go = gp ? actB : pB_;
            cc1 = fmaf(gf, cc1, gi * gg);
            const float h1v = go * tanh_(cc1);
            if (gp == 0) h1s[wb][j1] = h1v;
        } else if (t > 0) {
            // ---------------- layer 2, step t-1 (pipelined) ----------------
            const float4 vh2 = ((const float4*)h2s[rb])[l & 7];
            float a0=0.f,a1=0.f,a2=0.f,a3=0.f;
            #pragma unroll
            for (int k = 0; k < 16; ++k) {
                a0 = fmaf(wA[k].x, rlane(vh1.x, k), a0);
                a1 = fmaf(wA[k].y, rlane(vh1.y, k), a1);
                a2 = fmaf(wA[k].z, rlane(vh1.z, k), a2);
                a3 = fmaf(wA[k].w, rlane(vh1.w, k), a3);
            }
            #pragma unroll
            for (int k = 0; k < 8; ++k) {
                a0 = fmaf(wB[k].x, rlane(vh2.x, k), a0);
                a1 = fmaf(wB[k].y, rlane(vh2.y, k), a1);
                a2 = fmaf(wB[k].z, rlane(vh2.z, k), a2);
                a3 = fmaf(wB[k].w, rlane(vh2.w, k), a3);
            }
            const float pre2 = bbA + ((a0+a1)+(a2+a3));
            const float act2 = (g2 == 2) ? tanh_(pre2) : sigm(pre2);
            const float i2 = qperm<0x00>(act2);
            const float f2 = qperm<0x55>(act2);
            const float g2v= qperm<0xAA>(act2);
            const float o2 = qperm<0xFF>(act2);
            cc2 = fmaf(f2, cc2, i2 * g2v);
            const float h2v = o2 * tanh_(cc2);
            if (g2 == 0) h2s[wb][u2] = h2v;
        }
        __syncthreads();
    }

    // ---- epilogue: layer 2, step TT-1 ----
    // h1(4095) in h1s[0]; h2(4094) in h2s[0].
    if (!isL1) {
        const float4 vh1 = ((const float4*)h1s[0])[l & 15];
        const float4 vh2 = ((const float4*)h2s[0])[l & 7];
        float a0=0.f,a1=0.f,a2=0.f,a3=0.f;
        #pragma unroll
        for (int k = 0; k < 16; ++k) {
            a0 = fmaf(wA[k].x, rlane(vh1.x, k), a0);
            a1 = fmaf(wA[k].y, rlane(vh1.y, k), a1);
            a2 = fmaf(wA[k].z, rlane(vh1.z, k), a2);
            a3 = fmaf(wA[k].w, rlane(vh1.w, k), a3);
        }
        #pragma unroll
        for (int k = 0; k < 8; ++k) {
            a0 = fmaf(wB[k].x, rlane(vh2.x, k), a0);
            a1 = fmaf(wB[k].y, rlane(vh2.y, k), a1);
            a2 = fmaf(wB[k].z, rlane(vh2.z, k), a2);
            a3 = fmaf(wB[k].w, rlane(vh2.w, k), a3);
        }
        const float pre2 = bbA + ((a0+a1)+(a2+a3));
        const float act2 = (g2 == 2) ? tanh_(pre2) : sigm(pre2);
        const float i2 = qperm<0x00>(act2);
        const float f2 = qperm<0x55>(act2);
        const float g2v= qperm<0xAA>(act2);
        const float o2 = qperm<0xFF>(act2);
        cc2 = fmaf(f2, cc2, i2 * g2v);
        const float h2v = o2 * tanh_(cc2);
        if (g2 == 0) h2s[1][u2] = h2v;
    }
    __syncthreads();

    if (tid < 16) {
        float s = bfc[tid];
        const float* wr = Wfc + tid * 32;
        #pragma unroll
        for (int k = 0; k < 32; ++k) s = fmaf(wr[k], h2s[1][k], s);
        out[b * 16 + tid] = s;
    }
}

extern "C" void kernel_launch(void* const* d_in, const int* in_sizes, int n_in,
                              void* d_out, int out_size, void* d_ws, size_t ws_size,
                              hipStream_t stream) {
    const float* x    = (const float*)d_in[0];
    const float* Wih1 = (const float*)d_in[1];
    const float* Whh1 = (const float*)d_in[2];
    const float* bih1 = (const float*)d_in[3];
    const float* bhh1 = (const float*)d_in[4];
    const float* Wih2 = (const float*)d_in[5];
    const float* Whh2 = (const float*)d_in[6];
    const float* bih2 = (const float*)d_in[7];
    const float* bhh2 = (const float*)d_in[8];
    const float* Wfc  = (const float*)d_in[9];
    const float* bfc  = (const float*)d_in[10];

    lstm_enc_kernel<<<dim3(BB), dim3(256), 0, stream>>>(
        x, Wih1, Whh1, bih1, bhh1, Wih2, Whh2, bih2, bhh2, Wfc, bfc,
        (float*)d_out);
}

// Round 4
// 3074.898 us; speedup vs baseline: 1.7989x; 1.6351x over previous
//
#include <hip/hip_runtime.h>

// Encoder: 2-layer LSTM (H1=64, H2=32, IN=2), B=512, T=4096, + FC [32->16].
// R4: R3's wave-specialized pipelined structure with two structural fixes:
//  (1) Weights in 32 INDIVIDUALLY NAMED float4 SSA values (no arrays/allocas)
//      -- R2/R3's VGPR_Count=80/84 proved array-based weights were demoted to
//      scratch and re-streamed every step.
//  (2) isL1 made provably wave-uniform via readfirstlane -> s_cbranch, so each
//      wave executes ONLY its own body (R3 executed both under exec masks:
//      measured ~470 instr/wave/step == L1 body + L2 body).
// Roles: waves 2,3 = layer 1 (2 gate-rows/lane); waves 0,1 = layer 2 (1 row/lane),
// running one step behind layer 1; single barrier per step.

#define TT 4096
#define BB 512

__device__ __forceinline__ float fexp2(float x){ return __builtin_amdgcn_exp2f(x); }
__device__ __forceinline__ float frcp (float x){ return __builtin_amdgcn_rcpf(x); }
__device__ __forceinline__ float sigm (float x){ return frcp(1.0f + fexp2(x * -1.4426950408889634f)); }
__device__ __forceinline__ float tanh_(float x){ return 1.0f - 2.0f * frcp(1.0f + fexp2(x * 2.8853900817779268f)); }

__device__ __forceinline__ float rlane(float v, int lane){
  return __builtin_bit_cast(float, __builtin_amdgcn_readlane(__builtin_bit_cast(int, v), lane));
}
template<int CTRL>
__device__ __forceinline__ float qperm(float v){
  const int s = __builtin_bit_cast(int, v);
  return __builtin_bit_cast(float, __builtin_amdgcn_update_dpp(s, s, CTRL, 0xF, 0xF, true));
}

__global__ __launch_bounds__(256, 2) void lstm_enc_kernel(
    const float* __restrict__ x,
    const float* __restrict__ Wih1, const float* __restrict__ Whh1,
    const float* __restrict__ bih1, const float* __restrict__ bhh1,
    const float* __restrict__ Wih2, const float* __restrict__ Whh2,
    const float* __restrict__ bih2, const float* __restrict__ bhh2,
    const float* __restrict__ Wfc,  const float* __restrict__ bfc,
    float* __restrict__ out)
{
    const int tid = threadIdx.x;
    const int l   = tid & 63;
    // wave id as a PROVABLY SCALAR value -> s_cbranch on isL1, not exec-masking
    const int wv  = __builtin_amdgcn_readfirstlane(tid >> 6);
    const bool isL1 = (wv >= 2);
    const int b   = blockIdx.x;

    __shared__ float h1s[2][64];
    __shared__ float h2s[2][32];

    // ---- role indices ----
    const int j1  = (wv & 1) * 32 + (l >> 1);   // L1 unit (waves 2,3)
    const int gp  = l & 1;                      // 0: rows(i,f)  1: rows(g,o)
    const int rA1 = (2 * gp) * 64 + j1;
    const int rB1 = rA1 + 64;

    const int u2   = (wv & 1) * 16 + (l >> 2);  // L2 unit (waves 0,1)
    const int g2   = l & 3;                     // gate class
    const int row2 = g2 * 32 + u2;

    const int rA_s = isL1 ? rA1 : 0;
    const int rB_s = isL1 ? rB1 : 0;
    const int r2_s = isL1 ? 0   : row2;

    // ---- weight base pointers (address select; loads unconditional) ----
    const float4* pA  = (const float4*)(isL1 ? (Whh1 + rA1 * 64)      : (Wih2 + row2 * 64));
    const float4* pB1 = (const float4*)(isL1 ? (Whh1 + rB1 * 64)      : (Whh2 + row2 * 32));
    const float4* pB2 = (const float4*)(isL1 ? (Whh1 + rB1 * 64 + 32) : (Whh2 + row2 * 32));

    // ---- 32 named float4 = 128 weight VGPRs, no allocas anywhere ----
    float4 wA0 = pA[0],  wA1 = pA[1],  wA2 = pA[2],  wA3 = pA[3];
    float4 wA4 = pA[4],  wA5 = pA[5],  wA6 = pA[6],  wA7 = pA[7];
    float4 wA8 = pA[8],  wA9 = pA[9],  wA10 = pA[10], wA11 = pA[11];
    float4 wA12 = pA[12], wA13 = pA[13], wA14 = pA[14], wA15 = pA[15];
    float4 wB0 = pB1[0], wB1 = pB1[1], wB2 = pB1[2], wB3 = pB1[3];
    float4 wB4 = pB1[4], wB5 = pB1[5], wB6 = pB1[6], wB7 = pB1[7];
    float4 wB8 = pB2[0], wB9 = pB2[1], wB10 = pB2[2], wB11 = pB2[3];
    float4 wB12 = pB2[4], wB13 = pB2[5], wB14 = pB2[6], wB15 = pB2[7];

    const float bbA = isL1 ? (bih1[rA_s] + bhh1[rA_s]) : (bih2[r2_s] + bhh2[r2_s]);
    const float bbB = bih1[rB_s] + bhh1[rB_s];
    const float wxA0 = Wih1[rA_s * 2 + 0], wxA1 = Wih1[rA_s * 2 + 1];
    const float wxB0 = Wih1[rB_s * 2 + 0], wxB1 = Wih1[rB_s * 2 + 1];

    const float gpf = (float)gp;                    // L1 activation blend
    const float g2t = (g2 == 2) ? 1.0f : 0.0f;      // L2 activation blend

    const float* xb = x + (size_t)b * (TT * 2);
    float2 vx = make_float2(0.f, 0.f), vxn = make_float2(0.f, 0.f);
    if (isL1) vxn = ((const float2*)xb)[l];         // chunk 0

    if (tid < 64) h1s[0][tid] = 0.0f;
    if (tid < 32) { h2s[0][tid] = 0.0f; h2s[1][tid] = 0.0f; }
    __syncthreads();

    float cc1 = 0.0f, cc2 = 0.0f;

#define L1K(K) { \
    const float s0 = rlane(vh1.x, K); \
    const float s1 = rlane(vh1.y, K); \
    const float s2 = rlane(vh1.z, K); \
    const float s3 = rlane(vh1.w, K); \
    aA0 = fmaf(wA##K.x, s0, aA0); aB0 = fmaf(wB##K.x, s0, aB0); \
    aA1 = fmaf(wA##K.y, s1, aA1); aB1 = fmaf(wB##K.y, s1, aB1); \
    aA2 = fmaf(wA##K.z, s2, aA2); aB2 = fmaf(wB##K.z, s2, aB2); \
    aA3 = fmaf(wA##K.w, s3, aA3); aB3 = fmaf(wB##K.w, s3, aB3); }

#define L2A(K) { \
    a0 = fmaf(wA##K.x, rlane(vh1.x, K), a0); \
    a1 = fmaf(wA##K.y, rlane(vh1.y, K), a1); \
    a2 = fmaf(wA##K.z, rlane(vh1.z, K), a2); \
    a3 = fmaf(wA##K.w, rlane(vh1.w, K), a3); }

#define L2B(K) { \
    a0 = fmaf(wB##K.x, rlane(vh2.x, K), a0); \
    a1 = fmaf(wB##K.y, rlane(vh2.y, K), a1); \
    a2 = fmaf(wB##K.z, rlane(vh2.z, K), a2); \
    a3 = fmaf(wB##K.w, rlane(vh2.w, K), a3); }

    // t in [0, TT]: L1 computes step t (t<TT); L2 computes step t-1 (t>0).
    for (int t = 0; t <= TT; ++t) {
        const int rb = t & 1;
        const int wb = rb ^ 1;

        // h1(t-1), lane-distributed: lane m in [0,16) holds h1[4m..4m+3]
        const float4 vh1 = ((const float4*)h1s[rb])[l & 15];

        if (isL1) {
            if (t < TT) {
                if ((t & 63) == 0) {
                    vx = vxn;
                    if (t + 64 < TT) vxn = ((const float2*)xb)[(t >> 6) * 64 + 64 + l];
                }
                const float x0 = rlane(vx.x, t & 63);
                const float x1 = rlane(vx.y, t & 63);

                float aA0=0.f,aA1=0.f,aA2=0.f,aA3=0.f;
                float aB0=0.f,aB1=0.f,aB2=0.f,aB3=0.f;
                L1K(0)  L1K(1)  L1K(2)  L1K(3)  L1K(4)  L1K(5)  L1K(6)  L1K(7)
                L1K(8)  L1K(9)  L1K(10) L1K(11) L1K(12) L1K(13) L1K(14) L1K(15)
                const float preA = ((aA0+aA1)+(aA2+aA3)) + fmaf(wxA0, x0, fmaf(wxA1, x1, bbA));
                const float preB = ((aB0+aB1)+(aB2+aB3)) + fmaf(wxB0, x0, fmaf(wxB1, x1, bbB));

                // actA: sigm for gp=0 (i-row), tanh for gp=1 (g-row), branchless:
                // tanh(x) = 2*sigm(2x) - 1
                const float pa   = fmaf(gpf, preA, preA);       // x or 2x
                const float sa   = sigm(pa);
                const float actA = fmaf(gpf, sa - 1.0f, sa);    // s or 2s-1
                const float actB = sigm(preB);                  // f-row / o-row

                const float pA_ = qperm<0xB1>(actA);            // pair swap
                const float pB_ = qperm<0xB1>(actB);
                const float gi = gp ? pA_  : actA;
                const float gf = gp ? pB_  : actB;
                const float gg = gp ? actA : pA_;
                const float go = gp ? actB : pB_;
                cc1 = fmaf(gf, cc1, gi * gg);
                const float h1v = go * tanh_(cc1);
                if (gp == 0) h1s[wb][j1] = h1v;
            }
        } else if (t > 0) {
            // layer 2, step t-1: h2(t-2) lane-distributed (lane m<8: h2[4m..4m+3])
            const float4 vh2 = ((const float4*)h2s[rb])[l & 7];
            float a0=0.f,a1=0.f,a2=0.f,a3=0.f;
            L2A(0)  L2A(1)  L2A(2)  L2A(3)  L2A(4)  L2A(5)  L2A(6)  L2A(7)
            L2A(8)  L2A(9)  L2A(10) L2A(11) L2A(12) L2A(13) L2A(14) L2A(15)
            L2B(0)  L2B(1)  L2B(2)  L2B(3)  L2B(4)  L2B(5)  L2B(6)  L2B(7)
            const float pre2 = bbA + ((a0+a1)+(a2+a3));

            const float p2   = fmaf(g2t, pre2, pre2);
            const float s2v  = sigm(p2);
            const float act2 = fmaf(g2t, s2v - 1.0f, s2v);

            const float i2 = qperm<0x00>(act2);
            const float f2 = qperm<0x55>(act2);
            const float g2v= qperm<0xAA>(act2);
            const float o2 = qperm<0xFF>(act2);
            cc2 = fmaf(f2, cc2, i2 * g2v);
            const float h2v = o2 * tanh_(cc2);
            if (g2 == 0) h2s[wb][u2] = h2v;
        }
        __syncthreads();
    }

    // Loop ran through t=TT: h2(TT-1) was written to h2s[1] (wb at t=TT).
    if (tid < 16) {
        float s = bfc[tid];
        const float* wr = Wfc + tid * 32;
        #pragma unroll
        for (int k = 0; k < 32; ++k) s = fmaf(wr[k], h2s[1][k], s);
        out[b * 16 + tid] = s;
    }
#undef L1K
#undef L2A
#undef L2B
}

extern "C" void kernel_launch(void* const* d_in, const int* in_sizes, int n_in,
                              void* d_out, int out_size, void* d_ws, size_t ws_size,
                              hipStream_t stream) {
    const float* x    = (const float*)d_in[0];
    const float* Wih1 = (const float*)d_in[1];
    const float* Whh1 = (const float*)d_in[2];
    const float* bih1 = (const float*)d_in[3];
    const float* bhh1 = (const float*)d_in[4];
    const float* Wih2 = (const float*)d_in[5];
    const float* Whh2 = (const float*)d_in[6];
    const float* bih2 = (const float*)d_in[7];
    const float* bhh2 = (const float*)d_in[8];
    const float* Wfc  = (const float*)d_in[9];
    const float* bfc  = (const float*)d_in[10];

    lstm_enc_kernel<<<dim3(BB), dim3(256), 0, stream>>>(
        x, Wih1, Whh1, bih1, bhh1, Wih2, Whh2, bih2, bhh2, Wfc, bfc,
        (float*)d_out);
}